// Round 15
// baseline (131.533 us; speedup 1.0000x reference)
//
#include <hip/hip_runtime.h>

typedef __bf16 bf16x8 __attribute__((ext_vector_type(8)));
typedef float f32x4 __attribute__((ext_vector_type(4)));
typedef float f32x16 __attribute__((ext_vector_type(16)));
typedef unsigned u32x4 __attribute__((ext_vector_type(4)));

#define DEV __device__ __forceinline__
#define L2E 1.44269504f

// ---------- helpers ----------
DEV unsigned short f2bf(float f) {  // round-to-nearest-even f32 -> bf16
  unsigned u = __float_as_uint(f);
  u += 0x7fffu + ((u >> 16) & 1u);
  return (unsigned short)(u >> 16);
}
DEV float bf2f(unsigned short h) { return __uint_as_float(((unsigned)h) << 16); }

DEV void gload16(const void* g, void* l) {
  // async global->LDS; LDS dest must be wave-uniform (HW adds lane*16)
  __builtin_amdgcn_global_load_lds((const __attribute__((address_space(1))) void*)g,
                                   (__attribute__((address_space(3))) void*)l, 16, 0, 0);
}

DEV unsigned cvtpk2(float lo, float hi) {  // dword = {bf16(lo), bf16(hi)<<16}
  unsigned r;
  asm("v_cvt_pk_bf16_f32 %0, %1, %2" : "=v"(r) : "v"(lo), "v"(hi));
  return r;
}
DEV void plswap(unsigned& a, unsigned& b) {  // a.hi_lanes <-> b.lo_lanes
  asm volatile("v_permlane32_swap_b32 %0, %1" : "+v"(a), "+v"(b));
}
DEV float ex2(float x) {  // 2^x, single v_exp_f32
  float r;
  asm("v_exp_f32 %0, %1" : "=v"(r) : "v"(x));
  return r;
}
DEV float max3(float a, float b, float c) {
  float r;
  asm("v_max3_f32 %0, %1, %2, %3" : "=v"(r) : "v"(a), "v"(b), "v"(c));
  return r;
}

// Fragment-ordered tile layout (per 64-row x 128B tile, 8192B):
//   element (row, kbyte) lives at ((kbyte>>5)*2 + (row>>5))*1024
//                              + ((kbyte>>4)&1)*512 + (row&31)*16 + (kbyte&15)
// so an MFMA A/B fragment read for chunk (dc, half) is ds_read_b128 at
//   base + (dc*2+half)*1024 + lane*16   -- lane-linear, bank-conflict-free.

// ---------- fp32 -> bf16 converts (single dispatch) ----------
__global__ __launch_bounds__(256) void cvt7(const float* xq, const float* xk, const float* xv,
                                            const float* wq, const float* wk, const float* wv,
                                            const float* wp, ushort4* xqb, ushort4* xkb,
                                            ushort4* xvb, ushort4* wqb, ushort4* wkb,
                                            ushort4* wvb, ushort4* wpb, int nx4, int nw4) {
  const int y = blockIdx.y;
  const float4* s;
  ushort4* d;
  int n;
  switch (y) {
    case 0: s = (const float4*)xq; d = xqb; n = nx4; break;
    case 1: s = (const float4*)xk; d = xkb; n = nx4; break;
    case 2: s = (const float4*)xv; d = xvb; n = nx4; break;
    case 3: s = (const float4*)wq; d = wqb; n = nw4; break;
    case 4: s = (const float4*)wk; d = wkb; n = nw4; break;
    case 5: s = (const float4*)wv; d = wvb; n = nw4; break;
    default: s = (const float4*)wp; d = wpb; n = nw4; break;
  }
  for (int i = blockIdx.x * 256 + threadIdx.x; i < n; i += gridDim.x * 256) {
    float4 v = s[i];
    ushort4 o;
    o.x = f2bf(v.x); o.y = f2bf(v.y); o.z = f2bf(v.z); o.w = f2bf(v.w);
    d[i] = o;
  }
}

// ---------- GEMM core: 128x128 tile, BK=64, single-buffer, 2 barriers/step ----------
template <bool SWAP>
DEV void gemm_core(const unsigned short* __restrict__ A, const unsigned short* __restrict__ W,
                   char* sA, char* sB, f32x4 acc[4][4], int bm, int bn, int tid) {
  const int w = tid >> 6, lane = tid & 63;
  const int wm = w >> 1, wn = w & 1;
  const char* aB = (const char*)A + ((size_t)(bm * 128 + (lane >> 3)) << 11) +
                   (((lane & 7) ^ (lane >> 3)) << 4);
  const char* bB = (const char*)W + ((size_t)(bn * 128 + (lane >> 3)) << 11) +
                   (((lane & 7) ^ (lane >> 3)) << 4);
  const int ldsBase = w * 1024;

  for (int kt = 0; kt < 16; ++kt) {
    const int ko = kt * 128;
#pragma unroll
    for (int c = 0; c < 4; ++c) {
      gload16(aB + ((size_t)(c * 32 + w * 8) << 11) + ko, sA + c * 4096 + ldsBase);
      gload16(bB + ((size_t)(c * 32 + w * 8) << 11) + ko, sB + c * 4096 + ldsBase);
    }
    __syncthreads();
#pragma unroll
    for (int kk = 0; kk < 2; ++kk) {
      const int ch = ((kk * 4 + (lane >> 4)) ^ (lane & 7)) << 4;
      bf16x8 aF[4], bF[4];
#pragma unroll
      for (int mi = 0; mi < 4; ++mi)
        aF[mi] = *(const bf16x8*)(sA + (wm * 64 + mi * 16 + (lane & 15)) * 128 + ch);
#pragma unroll
      for (int ni = 0; ni < 4; ++ni)
        bF[ni] = *(const bf16x8*)(sB + (wn * 64 + ni * 16 + (lane & 15)) * 128 + ch);
#pragma unroll
      for (int mi = 0; mi < 4; ++mi)
#pragma unroll
        for (int ni = 0; ni < 4; ++ni)
          acc[mi][ni] = SWAP ? __builtin_amdgcn_mfma_f32_16x16x32_bf16(bF[ni], aF[mi],
                                                                       acc[mi][ni], 0, 0, 0)
                             : __builtin_amdgcn_mfma_f32_16x16x32_bf16(aF[mi], bF[ni],
                                                                       acc[mi][ni], 0, 0, 0);
    }
    __syncthreads();
  }
}

// Fused QKV projections. z=0: Q -> LN + fragment-order pack (scale 0.125*L2E),
// z=1: K -> LN + fragment-order pack, z=2: V -> V^T fragment-order pack.
__global__ __launch_bounds__(256, 3) void gemm_qkv(
    const unsigned short* __restrict__ xq, const unsigned short* __restrict__ xk,
    const unsigned short* __restrict__ xv, const unsigned short* __restrict__ wq,
    const unsigned short* __restrict__ wk, const unsigned short* __restrict__ wv,
    unsigned short* __restrict__ qh, unsigned short* __restrict__ kh,
    unsigned short* __restrict__ vt) {
  __shared__ char sA[16384], sB[16384];
  const int z = blockIdx.z;
  const int flat = blockIdx.x + (blockIdx.y << 3);
  const int xcd = flat & 7, ii = flat >> 3;
  const int bm = xcd * 4 + (ii >> 3), bn = ii & 7;
  const int tid = threadIdx.x, w = tid >> 6, lane = tid & 63;
  const int wm = w >> 1, wn = w & 1;

  if (z == 2) {
    f32x4 acc[4][4];
#pragma unroll
    for (int i = 0; i < 4; ++i)
#pragma unroll
      for (int j = 0; j < 4; ++j) acc[i][j] = (f32x4){0.f, 0.f, 0.f, 0.f};
    gemm_core<false>(xv, wv, sA, sB, acc, bm, bn, tid);
    // V^T tile rows = d, cols = kv. acc gives 4 consecutive kv rows per (mi,ni).
    const int hb = bn * 2 + wn;
    const int d = (lane & 15);
    const int g0 = bm * 128 + wm * 64 + ((lane >> 4) << 2);
#pragma unroll
    for (int mi = 0; mi < 4; ++mi) {
      const int g = g0 + mi * 16;
      const int b = g >> 11, n0 = g & 2047, tq = n0 >> 6, nn = n0 & 63;
#pragma unroll
      for (int ni = 0; ni < 4; ++ni) {
        const int dd = d + ni * 16;
        char* dst = (char*)vt + ((size_t)((b * 16 + hb) * 32 + tq) << 13) +
                    (((nn >> 4) * 2 + (dd >> 5)) << 10) + (((nn >> 3) & 1) << 9) +
                    ((dd & 31) << 4) + ((nn & 7) << 1);
        *(uint2*)dst = make_uint2(cvtpk2(acc[mi][ni][0], acc[mi][ni][1]),
                                  cvtpk2(acc[mi][ni][2], acc[mi][ni][3]));
      }
    }
  } else {
    const unsigned short* A = z == 0 ? xq : xk;
    const unsigned short* W = z == 0 ? wq : wk;
    f32x4 acc[4][4];
#pragma unroll
    for (int i = 0; i < 4; ++i)
#pragma unroll
      for (int j = 0; j < 4; ++j) acc[i][j] = (f32x4){0.f, 0.f, 0.f, 0.f};
    gemm_core<true>(A, W, sA, sB, acc, bm, bn, tid);
    unsigned short* dst = z == 0 ? qh : kh;
    const float osc = z == 0 ? 0.125f * L2E : 1.0f;
    const int h = bn * 2 + wn;
    const int hiK = lane >> 5;            // k-half bit of the 16B frag
    const int low8 = ((lane >> 4) & 1) << 3;
#pragma unroll
    for (int mi = 0; mi < 4; ++mi) {
      float s = 0.f, ss = 0.f;
#pragma unroll
      for (int ni = 0; ni < 4; ++ni)
#pragma unroll
        for (int r = 0; r < 4; ++r) {
          const float v = acc[mi][ni][r];
          s += v;
          ss += v * v;
        }
      s += __shfl_xor(s, 16); ss += __shfl_xor(ss, 16);
      s += __shfl_xor(s, 32); ss += __shfl_xor(ss, 32);
      const float mean = s * 0.015625f;
      const float var = ss * 0.015625f - mean * mean;
      const float rstd = rsqrtf(var + 1e-5f) * osc;
      const float mr = mean * rstd;
      const int g = bm * 128 + wm * 64 + mi * 16 + (lane & 15);
      const int b = g >> 11, n = g & 2047;
      const int bh = b * 16 + h, tq = n >> 6, rr = n & 63;
      char* tbase = (char*)dst + ((size_t)(bh * 32 + tq) << 13);
#pragma unroll
      for (int ni = 0; ni < 4; ++ni) {
        const unsigned u0 = cvtpk2(fmaf(acc[mi][ni][0], rstd, -mr), fmaf(acc[mi][ni][1], rstd, -mr));
        const unsigned u1 = cvtpk2(fmaf(acc[mi][ni][2], rstd, -mr), fmaf(acc[mi][ni][3], rstd, -mr));
        char* p = tbase + ((ni * 2 + (rr >> 5)) << 10) + (hiK << 9) + ((rr & 31) << 4) + low8;
        *(uint2*)p = make_uint2(u0, u1);
      }
    }
  }
}

// ---------- final projection with FUSED 2-way split-KV merge ----------
// 128x64 tile, BK=64 (= one head per K-step). A is reg-staged: batch-load both
// opart halves' 16B chunks + (m,l), merge in-register, ds_write_b128 to the SAME
// linear LDS slot global_load_lds would fill (chunk pre-XOR'd: slot = ch^(row&7)).
// launch_bounds (256,2): 512 blocks = 2/CU anyway; doubles VGPR budget -> no spill
// (R12's regression was the (256,3) ~85-VGPR cap spilling the staging set).
__global__ __launch_bounds__(256, 2) void gemm_out(const unsigned short* __restrict__ Op,
                                                   const float2* __restrict__ ML,
                                                   const unsigned short* __restrict__ Wp,
                                                   float* __restrict__ C) {
  __shared__ char sA[16384], sB[8192];
  const int flat = blockIdx.x + (blockIdx.y << 4);  // grid (16,32)
  const int xcd = flat & 7, ii = flat >> 3;
  const int bm = xcd * 4 + (ii & 3), bn = ii >> 2;
  const int tid = threadIdx.x, w = tid >> 6, lane = tid & 63;
  const int wm = w >> 1, wn = w & 1;
  f32x4 acc[4][2];
#pragma unroll
  for (int i = 0; i < 4; ++i)
#pragma unroll
    for (int j = 0; j < 2; ++j) acc[i][j] = (f32x4){0.f, 0.f, 0.f, 0.f};

  const char* bB = (const char*)Wp + ((size_t)(bn * 64 + (lane >> 3)) << 11) +
                   (((lane & 7) ^ (lane >> 3)) << 4);
  const int ldsBase = w * 1024;
  const int rsub = lane >> 3;                 // row within 8-row group
  const int ch8 = (lane & 7) ^ rsub;          // XOR-swizzled chunk 0..7
  const int d0 = ch8 * 8;                     // d offset within head

  for (int kt = 0; kt < 16; ++kt) {           // kt == head h
    const int ko = kt * 128;
#pragma unroll
    for (int c = 0; c < 2; ++c)
      gload16(bB + ((size_t)(c * 32 + w * 8) << 11) + ko, sB + c * 4096 + ldsBase);
    // batch-issue all partial loads (MLP: one round-trip latency)
    uint4 pa[4], pb[4];
    float2 mla[4], mlb[4];
#pragma unroll
    for (int c = 0; c < 4; ++c) {
      const int grow = bm * 128 + c * 32 + w * 8 + rsub;
      const int b = grow >> 11, q = grow & 2047;
      const size_t pr0 = (size_t)(b * 16 + kt) * 2048 + q;   // half 0
      const size_t pr1 = pr0 + 65536;                        // half 1 (+32*2048)
      pa[c] = *(const uint4*)(Op + pr0 * 64 + d0);
      pb[c] = *(const uint4*)(Op + pr1 * 64 + d0);
      mla[c] = ML[pr0];
      mlb[c] = ML[pr1];
    }
#pragma unroll
    for (int c = 0; c < 4; ++c) {
      const float mm = fmaxf(mla[c].x, mlb[c].x);
      float w0 = mla[c].y * ex2(mla[c].x - mm);
      float w1 = mlb[c].y * ex2(mlb[c].x - mm);
      const float inv = 1.f / (w0 + w1);
      w0 *= inv; w1 *= inv;
      const unsigned av[4] = {pa[c].x, pa[c].y, pa[c].z, pa[c].w};
      const unsigned bv[4] = {pb[c].x, pb[c].y, pb[c].z, pb[c].w};
      unsigned ov[4];
#pragma unroll
      for (int j = 0; j < 4; ++j) {
        const float r0 = w0 * bf2f((unsigned short)(av[j] & 0xffff)) +
                         w1 * bf2f((unsigned short)(bv[j] & 0xffff));
        const float r1 = w0 * bf2f((unsigned short)(av[j] >> 16)) +
                         w1 * bf2f((unsigned short)(bv[j] >> 16));
        ov[j] = cvtpk2(r0, r1);
      }
      *(u32x4*)(sA + c * 4096 + ldsBase + lane * 16) = (u32x4){ov[0], ov[1], ov[2], ov[3]};
    }
    __syncthreads();
#pragma unroll
    for (int kk = 0; kk < 2; ++kk) {
      const int ch = ((kk * 4 + (lane >> 4)) ^ (lane & 7)) << 4;
      bf16x8 aF[4], bF[2];
#pragma unroll
      for (int mi = 0; mi < 4; ++mi)
        aF[mi] = *(const bf16x8*)(sA + (wm * 64 + mi * 16 + (lane & 15)) * 128 + ch);
#pragma unroll
      for (int ni = 0; ni < 2; ++ni)
        bF[ni] = *(const bf16x8*)(sB + (wn * 32 + ni * 16 + (lane & 15)) * 128 + ch);
#pragma unroll
      for (int mi = 0; mi < 4; ++mi)
#pragma unroll
        for (int ni = 0; ni < 2; ++ni)
          acc[mi][ni] = __builtin_amdgcn_mfma_f32_16x16x32_bf16(bF[ni], aF[mi], acc[mi][ni], 0, 0, 0);
    }
    __syncthreads();
  }
  const int m0 = bm * 128 + wm * 64 + (lane & 15);
  const int nb = bn * 64 + wn * 32 + ((lane >> 4) << 2);
#pragma unroll
  for (int mi = 0; mi < 4; ++mi)
#pragma unroll
    for (int ni = 0; ni < 2; ++ni) {
      const f32x4 v = acc[mi][ni];
      *(float4*)&C[(size_t)(m0 + mi * 16) * 1024 + nb + ni * 16] =
          make_float4(v[0], v[1], v[2], v[3]);
    }
}

// ---------- flash attention: q=32/wave, max folded into acc-init, lacc MFMA, split-KV=2 ----------
// (R13 structure verbatim: best measured at 50.0 us)
__global__ __launch_bounds__(256, 4) void attn_fused(
    const unsigned short* __restrict__ Qp, const unsigned short* __restrict__ Kp,
    const unsigned short* __restrict__ Vp, unsigned short* __restrict__ Opart,
    float2* __restrict__ ML) {
  const int bid = blockIdx.x;
  const int xcd = bid & 7, idx = bid >> 3;  // idx 0..127
  const int bh = ((idx & 3) << 3) | xcd;    // bh % 8 == xcd
  const int rest = idx >> 2;                // 0..31
  const int half = rest & 1;
  const int qt = rest >> 1;                 // 0..15 (128-row Q blocks)
  __shared__ char smem[32768];
  const int tid = threadIdx.x, w = tid >> 6, lane = tid & 63;
  const int q5 = lane & 31, hi = lane >> 5;

  const char* qg = (const char*)Qp + ((size_t)(bh * 32 + qt * 2) << 13);
  const char* kg = (const char*)Kp + ((size_t)(bh * 32 + half * 16) << 13);
  const char* vg = (const char*)Vp + ((size_t)(bh * 32 + half * 16) << 13);

  // stage 2 Q tiles (16 KB), pull frags (lane-linear), then smem becomes KV dbuf
#pragma unroll
  for (int t = 0; t < 4; ++t)
    gload16(qg + (w * 4 + t) * 1024 + lane * 16, smem + (w * 4 + t) * 1024);
  __syncthreads();
  bf16x8 qf[4];
  {
    const int qbase = (w >> 1) * 8192 + ((w & 1) << 10);
#pragma unroll
    for (int dc = 0; dc < 4; ++dc)
      qf[dc] = *(const bf16x8*)(smem + qbase + (dc << 11) + lane * 16);
  }
  __syncthreads();

#pragma unroll
  for (int t = 0; t < 2; ++t) {
    gload16(kg + (w * 2 + t) * 1024 + lane * 16, smem + (w * 2 + t) * 1024);
    gload16(vg + (w * 2 + t) * 1024 + lane * 16, smem + 16384 + (w * 2 + t) * 1024);
  }

  // ones fragment for l-sum MFMA (bf16 1.0 = 0x3F80)
  const u32x4 onesw = {0x3F803F80u, 0x3F803F80u, 0x3F803F80u, 0x3F803F80u};
  const bf16x8 ones = __builtin_bit_cast(bf16x8, onesw);

  f32x16 o0 = {0,0,0,0,0,0,0,0,0,0,0,0,0,0,0,0};
  f32x16 o1 = {0,0,0,0,0,0,0,0,0,0,0,0,0,0,0,0};
  f32x16 lacc = {0,0,0,0,0,0,0,0,0,0,0,0,0,0,0,0};  // row sums of P~; read reg 0 only
  float m = 0.f;        // running max in log2 domain (scores bounded by ~11.6)
  float negm = 0.f;     // -m, the S-accumulator init value

  for (int kt = 0; kt < 16; ++kt) {
    const int cur = kt & 1;
    const int kOff = cur * 8192;
    const int vOff = 16384 + cur * 8192;
    __syncthreads();
    if (kt < 15) {
      const int kN = (cur ^ 1) * 8192, vN = 16384 + (cur ^ 1) * 8192;
#pragma unroll
      for (int t = 0; t < 2; ++t) {
        gload16(kg + (size_t)(kt + 1) * 8192 + (w * 2 + t) * 1024 + lane * 16,
                smem + kN + (w * 2 + t) * 1024);
        gload16(vg + (size_t)(kt + 1) * 8192 + (w * 2 + t) * 1024 + lane * 16,
                smem + vN + (w * 2 + t) * 1024);
      }
    }
    // S^T = K * Q^T + (-m)  (log2 domain, max pre-subtracted via acc init)
    f32x16 s0, s1;
#pragma unroll
    for (int r = 0; r < 16; ++r) { s0[r] = negm; s1[r] = negm; }
    __builtin_amdgcn_s_setprio(1);
#pragma unroll
    for (int dc = 0; dc < 4; ++dc) {
      const bf16x8 kf0 = *(const bf16x8*)(smem + kOff + (dc << 11) + lane * 16);
      const bf16x8 kf1 = *(const bf16x8*)(smem + kOff + (dc << 11) + 1024 + lane * 16);
      s0 = __builtin_amdgcn_mfma_f32_32x32x16_bf16(kf0, qf[dc], s0, 0, 0, 0);
      s1 = __builtin_amdgcn_mfma_f32_32x32x16_bf16(kf1, qf[dc], s1, 0, 0, 0);
    }
    __builtin_amdgcn_s_setprio(0);
    // shifted row max (values are S - m): v_max3 tree + cross-half swap
    float tt[12];
#pragma unroll
    for (int r = 0; r < 10; ++r) {
      const float a = (3 * r) < 16 ? s0[(3 * r) & 15] : s1[(3 * r) & 15];
      const float b = (3 * r + 1) < 16 ? s0[(3 * r + 1) & 15] : s1[(3 * r + 1) & 15];
      const float c = (3 * r + 2) < 16 ? s0[(3 * r + 2) & 15] : s1[(3 * r + 2) & 15];
      tt[r] = max3(a, b, c);
    }
    tt[10] = s1[14]; tt[11] = s1[15];
    tt[0] = max3(tt[0], tt[1], tt[2]);
    tt[1] = max3(tt[3], tt[4], tt[5]);
    tt[2] = max3(tt[6], tt[7], tt[8]);
    tt[3] = max3(tt[9], tt[10], tt[11]);
    const float loc = fmaxf(max3(tt[0], tt[1], tt[2]), tt[3]);
    const float mx = fmaxf(loc, __shfl_xor(loc, 32));  // = rowmax(S) - m
    if (__any(mx > 8.f)) {  // defer-max: rescale only when max grows materially
      const float exc = fmaxf(mx, 0.f);
      const float corr = ex2(-exc);
      lacc[0] *= corr;  // only reg 0 is ever read
#pragma unroll
      for (int r = 0; r < 16; ++r) { o0[r] *= corr; o1[r] *= corr; }
#pragma unroll
      for (int r = 0; r < 16; ++r) { s0[r] -= exc; s1[r] -= exc; }
      m += exc;
      negm = -m;
    }
    unsigned pk[4][4];
#define DO_CHUNK(c, SV, B)                                      \
  {                                                             \
    float p0 = ex2(SV[B + 0]);                                  \
    float p1 = ex2(SV[B + 1]);                                  \
    float p2 = ex2(SV[B + 2]);                                  \
    float p3 = ex2(SV[B + 3]);                                  \
    float p4 = ex2(SV[B + 4]);                                  \
    float p5 = ex2(SV[B + 5]);                                  \
    float p6 = ex2(SV[B + 6]);                                  \
    float p7 = ex2(SV[B + 7]);                                  \
    unsigned a0 = cvtpk2(p0, p1), a1 = cvtpk2(p2, p3);          \
    unsigned b0 = cvtpk2(p4, p5), b1 = cvtpk2(p6, p7);          \
    plswap(a0, b0);                                             \
    plswap(a1, b1);                                             \
    pk[c][0] = a0; pk[c][1] = a1; pk[c][2] = b0; pk[c][3] = b1; \
  }
    DO_CHUNK(0, s0, 0)
    DO_CHUNK(1, s0, 8)
    DO_CHUNK(2, s1, 0)
    DO_CHUNK(3, s1, 8)
#undef DO_CHUNK
    // O^T += V^T * P^T ; l += ones * P^T (row sums in matrix pipe)
    __builtin_amdgcn_s_setprio(1);
#pragma unroll
    for (int kk = 0; kk < 4; ++kk) {
      const bf16x8 vf0 = *(const bf16x8*)(smem + vOff + (kk << 11) + lane * 16);
      const bf16x8 vf1 = *(const bf16x8*)(smem + vOff + (kk << 11) + 1024 + lane * 16);
      const u32x4 pw = {pk[kk][0], pk[kk][1], pk[kk][2], pk[kk][3]};
      const bf16x8 pb = __builtin_bit_cast(bf16x8, pw);
      o0 = __builtin_amdgcn_mfma_f32_32x32x16_bf16(vf0, pb, o0, 0, 0, 0);
      o1 = __builtin_amdgcn_mfma_f32_32x32x16_bf16(vf1, pb, o1, 0, 0, 0);
      lacc = __builtin_amdgcn_mfma_f32_32x32x16_bf16(ones, pb, lacc, 0, 0, 0);
    }
    __builtin_amdgcn_s_setprio(0);
  }

  const float l = lacc[0];
  const float invl = 1.f / l;
  const int q = qt * 128 + w * 32 + q5;
  const size_t prow = (size_t)(half * 32 + bh) * 2048 + q;
  unsigned short* ob = Opart + prow * 64;
#pragma unroll
  for (int g = 0; g < 4; ++g) {
    unsigned d0 = cvtpk2(o0[4 * g + 0] * invl, o0[4 * g + 1] * invl);
    unsigned d1 = cvtpk2(o0[4 * g + 2] * invl, o0[4 * g + 3] * invl);
    *(uint2*)(ob + 8 * g + 4 * hi) = make_uint2(d0, d1);
    unsigned e0 = cvtpk2(o1[4 * g + 0] * invl, o1[4 * g + 1] * invl);
    unsigned e1 = cvtpk2(o1[4 * g + 2] * invl, o1[4 * g + 3] * invl);
    *(uint2*)(ob + 32 + 8 * g + 4 * hi) = make_uint2(e0, e1);
  }
  if (hi == 0) ML[prow] = make_float2(m, l);
}

// ---------- launch ----------
extern "C" void kernel_launch(void* const* d_in, const int* in_sizes, int n_in,
                              void* d_out, int out_size, void* d_ws, size_t ws_size,
                              hipStream_t stream) {
  const float* xq = (const float*)d_in[0];
  const float* xk = (const float*)d_in[1];
  const float* xv = (const float*)d_in[2];
  const float* wq = (const float*)d_in[3];
  const float* wk = (const float*)d_in[4];
  const float* wv = (const float*)d_in[5];
  const float* wp = (const float*)d_in[6];

  const size_t NX = 4194304;  // B*N*D
  const size_t NW = 1048576;  // D*D
  unsigned short* base = (unsigned short*)d_ws;
  unsigned short* xqb = base;
  unsigned short* xkb = base + NX;
  unsigned short* xvb = base + 2 * NX;
  unsigned short* wqb = base + 3 * NX;
  unsigned short* wkb = wqb + NW;
  unsigned short* wvb = wkb + NW;
  unsigned short* wpb = base + 3 * NX + 4 * NW;  // beyond opart region
  unsigned short* qh = wpb + NW;
  unsigned short* kh = qh + NX;
  unsigned short* vt = kh + NX;
  unsigned short* obf = vt + NX;                 // (unused; kept for layout)
  float2* ml = (float2*)(obf + NX);
  unsigned short* opart = base;  // aliases dead x bf16 buffers (2*NX used)

  cvt7<<<dim3(512, 7), 256, 0, stream>>>(xq, xk, xv, wq, wk, wv, wp, (ushort4*)xqb,
                                         (ushort4*)xkb, (ushort4*)xvb, (ushort4*)wqb,
                                         (ushort4*)wkb, (ushort4*)wvb, (ushort4*)wpb,
                                         (int)(NX / 4), (int)(NW / 4));

  gemm_qkv<<<dim3(8, 32, 3), 256, 0, stream>>>(xqb, xkb, xvb, wqb, wkb, wvb, qh, kh, vt);

  attn_fused<<<1024, 256, 0, stream>>>(qh, kh, vt, opart, ml);

  gemm_out<<<dim3(16, 32), 256, 0, stream>>>(opart, ml, wpb, (float*)d_out);
}

// Round 16
// 121.430 us; speedup vs baseline: 1.0832x; 1.0832x over previous
//
#include <hip/hip_runtime.h>

typedef __bf16 bf16x8 __attribute__((ext_vector_type(8)));
typedef float f32x4 __attribute__((ext_vector_type(4)));
typedef float f32x16 __attribute__((ext_vector_type(16)));
typedef unsigned u32x4 __attribute__((ext_vector_type(4)));

#define DEV __device__ __forceinline__
#define L2E 1.44269504f

// ---------- helpers ----------
DEV unsigned short f2bf(float f) {  // round-to-nearest-even f32 -> bf16
  unsigned u = __float_as_uint(f);
  u += 0x7fffu + ((u >> 16) & 1u);
  return (unsigned short)(u >> 16);
}
DEV float bf2f(unsigned short h) { return __uint_as_float(((unsigned)h) << 16); }

DEV void gload16(const void* g, void* l) {
  // async global->LDS; LDS dest must be wave-uniform (HW adds lane*16)
  __builtin_amdgcn_global_load_lds((const __attribute__((address_space(1))) void*)g,
                                   (__attribute__((address_space(3))) void*)l, 16, 0, 0);
}

DEV unsigned cvtpk2(float lo, float hi) {  // dword = {bf16(lo), bf16(hi)<<16}
  unsigned r;
  asm("v_cvt_pk_bf16_f32 %0, %1, %2" : "=v"(r) : "v"(lo), "v"(hi));
  return r;
}
DEV void plswap(unsigned& a, unsigned& b) {  // a.hi_lanes <-> b.lo_lanes
  asm volatile("v_permlane32_swap_b32 %0, %1" : "+v"(a), "+v"(b));
}
DEV float ex2(float x) {  // 2^x, single v_exp_f32
  float r;
  asm("v_exp_f32 %0, %1" : "=v"(r) : "v"(x));
  return r;
}
DEV float max3(float a, float b, float c) {
  float r;
  asm("v_max3_f32 %0, %1, %2, %3" : "=v"(r) : "v"(a), "v"(b), "v"(c));
  return r;
}

// Fragment-ordered tile layout (per 64-row x 128B tile, 8192B):
//   element (row, kbyte) lives at ((kbyte>>5)*2 + (row>>5))*1024
//                              + ((kbyte>>4)&1)*512 + (row&31)*16 + (kbyte&15)
// so an MFMA A/B fragment read for chunk (dc, half) is ds_read_b128 at
//   base + (dc*2+half)*1024 + lane*16   -- lane-linear, bank-conflict-free.

// ---------- fp32 -> bf16 converts (single dispatch) ----------
__global__ __launch_bounds__(256) void cvt7(const float* xq, const float* xk, const float* xv,
                                            const float* wq, const float* wk, const float* wv,
                                            const float* wp, ushort4* xqb, ushort4* xkb,
                                            ushort4* xvb, ushort4* wqb, ushort4* wkb,
                                            ushort4* wvb, ushort4* wpb, int nx4, int nw4) {
  const int y = blockIdx.y;
  const float4* s;
  ushort4* d;
  int n;
  switch (y) {
    case 0: s = (const float4*)xq; d = xqb; n = nx4; break;
    case 1: s = (const float4*)xk; d = xkb; n = nx4; break;
    case 2: s = (const float4*)xv; d = xvb; n = nx4; break;
    case 3: s = (const float4*)wq; d = wqb; n = nw4; break;
    case 4: s = (const float4*)wk; d = wkb; n = nw4; break;
    case 5: s = (const float4*)wv; d = wvb; n = nw4; break;
    default: s = (const float4*)wp; d = wpb; n = nw4; break;
  }
  for (int i = blockIdx.x * 256 + threadIdx.x; i < n; i += gridDim.x * 256) {
    float4 v = s[i];
    ushort4 o;
    o.x = f2bf(v.x); o.y = f2bf(v.y); o.z = f2bf(v.z); o.w = f2bf(v.w);
    d[i] = o;
  }
}

// ---------- GEMM core: 128x128 tile, BK=64, single-buffer, 2 barriers/step ----------
template <bool SWAP>
DEV void gemm_core(const unsigned short* __restrict__ A, const unsigned short* __restrict__ W,
                   char* sA, char* sB, f32x4 acc[4][4], int bm, int bn, int tid) {
  const int w = tid >> 6, lane = tid & 63;
  const int wm = w >> 1, wn = w & 1;
  const char* aB = (const char*)A + ((size_t)(bm * 128 + (lane >> 3)) << 11) +
                   (((lane & 7) ^ (lane >> 3)) << 4);
  const char* bB = (const char*)W + ((size_t)(bn * 128 + (lane >> 3)) << 11) +
                   (((lane & 7) ^ (lane >> 3)) << 4);
  const int ldsBase = w * 1024;

  for (int kt = 0; kt < 16; ++kt) {
    const int ko = kt * 128;
#pragma unroll
    for (int c = 0; c < 4; ++c) {
      gload16(aB + ((size_t)(c * 32 + w * 8) << 11) + ko, sA + c * 4096 + ldsBase);
      gload16(bB + ((size_t)(c * 32 + w * 8) << 11) + ko, sB + c * 4096 + ldsBase);
    }
    __syncthreads();
#pragma unroll
    for (int kk = 0; kk < 2; ++kk) {
      const int ch = ((kk * 4 + (lane >> 4)) ^ (lane & 7)) << 4;
      bf16x8 aF[4], bF[4];
#pragma unroll
      for (int mi = 0; mi < 4; ++mi)
        aF[mi] = *(const bf16x8*)(sA + (wm * 64 + mi * 16 + (lane & 15)) * 128 + ch);
#pragma unroll
      for (int ni = 0; ni < 4; ++ni)
        bF[ni] = *(const bf16x8*)(sB + (wn * 64 + ni * 16 + (lane & 15)) * 128 + ch);
#pragma unroll
      for (int mi = 0; mi < 4; ++mi)
#pragma unroll
        for (int ni = 0; ni < 4; ++ni)
          acc[mi][ni] = SWAP ? __builtin_amdgcn_mfma_f32_16x16x32_bf16(bF[ni], aF[mi],
                                                                       acc[mi][ni], 0, 0, 0)
                             : __builtin_amdgcn_mfma_f32_16x16x32_bf16(aF[mi], bF[ni],
                                                                       acc[mi][ni], 0, 0, 0);
    }
    __syncthreads();
  }
}

// Fused QKV projections. z=0: Q -> LN + fragment-order pack (scale 0.125*L2E),
// z=1: K -> LN + fragment-order pack, z=2: V -> V^T fragment-order pack.
__global__ __launch_bounds__(256, 3) void gemm_qkv(
    const unsigned short* __restrict__ xq, const unsigned short* __restrict__ xk,
    const unsigned short* __restrict__ xv, const unsigned short* __restrict__ wq,
    const unsigned short* __restrict__ wk, const unsigned short* __restrict__ wv,
    unsigned short* __restrict__ qh, unsigned short* __restrict__ kh,
    unsigned short* __restrict__ vt) {
  __shared__ char sA[16384], sB[16384];
  const int z = blockIdx.z;
  const int flat = blockIdx.x + (blockIdx.y << 3);
  const int xcd = flat & 7, ii = flat >> 3;
  const int bm = xcd * 4 + (ii >> 3), bn = ii & 7;
  const int tid = threadIdx.x, w = tid >> 6, lane = tid & 63;
  const int wm = w >> 1, wn = w & 1;

  if (z == 2) {
    f32x4 acc[4][4];
#pragma unroll
    for (int i = 0; i < 4; ++i)
#pragma unroll
      for (int j = 0; j < 4; ++j) acc[i][j] = (f32x4){0.f, 0.f, 0.f, 0.f};
    gemm_core<false>(xv, wv, sA, sB, acc, bm, bn, tid);
    // V^T tile rows = d, cols = kv. acc gives 4 consecutive kv rows per (mi,ni).
    const int hb = bn * 2 + wn;
    const int d = (lane & 15);
    const int g0 = bm * 128 + wm * 64 + ((lane >> 4) << 2);
#pragma unroll
    for (int mi = 0; mi < 4; ++mi) {
      const int g = g0 + mi * 16;
      const int b = g >> 11, n0 = g & 2047, tq = n0 >> 6, nn = n0 & 63;
#pragma unroll
      for (int ni = 0; ni < 4; ++ni) {
        const int dd = d + ni * 16;
        char* dst = (char*)vt + ((size_t)((b * 16 + hb) * 32 + tq) << 13) +
                    (((nn >> 4) * 2 + (dd >> 5)) << 10) + (((nn >> 3) & 1) << 9) +
                    ((dd & 31) << 4) + ((nn & 7) << 1);
        *(uint2*)dst = make_uint2(cvtpk2(acc[mi][ni][0], acc[mi][ni][1]),
                                  cvtpk2(acc[mi][ni][2], acc[mi][ni][3]));
      }
    }
  } else {
    const unsigned short* A = z == 0 ? xq : xk;
    const unsigned short* W = z == 0 ? wq : wk;
    f32x4 acc[4][4];
#pragma unroll
    for (int i = 0; i < 4; ++i)
#pragma unroll
      for (int j = 0; j < 4; ++j) acc[i][j] = (f32x4){0.f, 0.f, 0.f, 0.f};
    gemm_core<true>(A, W, sA, sB, acc, bm, bn, tid);
    unsigned short* dst = z == 0 ? qh : kh;
    const float osc = z == 0 ? 0.125f * L2E : 1.0f;
    const int h = bn * 2 + wn;
    const int hiK = lane >> 5;            // k-half bit of the 16B frag
    const int low8 = ((lane >> 4) & 1) << 3;
#pragma unroll
    for (int mi = 0; mi < 4; ++mi) {
      float s = 0.f, ss = 0.f;
#pragma unroll
      for (int ni = 0; ni < 4; ++ni)
#pragma unroll
        for (int r = 0; r < 4; ++r) {
          const float v = acc[mi][ni][r];
          s += v;
          ss += v * v;
        }
      s += __shfl_xor(s, 16); ss += __shfl_xor(ss, 16);
      s += __shfl_xor(s, 32); ss += __shfl_xor(ss, 32);
      const float mean = s * 0.015625f;
      const float var = ss * 0.015625f - mean * mean;
      const float rstd = rsqrtf(var + 1e-5f) * osc;
      const float mr = mean * rstd;
      const int g = bm * 128 + wm * 64 + mi * 16 + (lane & 15);
      const int b = g >> 11, n = g & 2047;
      const int bh = b * 16 + h, tq = n >> 6, rr = n & 63;
      char* tbase = (char*)dst + ((size_t)(bh * 32 + tq) << 13);
#pragma unroll
      for (int ni = 0; ni < 4; ++ni) {
        const unsigned u0 = cvtpk2(fmaf(acc[mi][ni][0], rstd, -mr), fmaf(acc[mi][ni][1], rstd, -mr));
        const unsigned u1 = cvtpk2(fmaf(acc[mi][ni][2], rstd, -mr), fmaf(acc[mi][ni][3], rstd, -mr));
        char* p = tbase + ((ni * 2 + (rr >> 5)) << 10) + (hiK << 9) + ((rr & 31) << 4) + low8;
        *(uint2*)p = make_uint2(u0, u1);
      }
    }
  }
}

// ---------- final projection: 128x64 tile, swapped acc, float4 out ----------
// (256,2): 512 blocks = 2/CU regardless (LDS caps at 5); doubled VGPR budget is
// free scheduling headroom vs the (256,3) ~85-reg cap.
__global__ __launch_bounds__(256, 2) void gemm_out(const unsigned short* __restrict__ A,
                                                   const unsigned short* __restrict__ Wp,
                                                   float* __restrict__ C) {
  __shared__ char sA[16384], sB[8192];
  const int flat = blockIdx.x + (blockIdx.y << 4);
  const int xcd = flat & 7, ii = flat >> 3;
  const int bm = xcd * 4 + (ii & 3), bn = ii >> 2;
  const int tid = threadIdx.x, w = tid >> 6, lane = tid & 63;
  const int wm = w >> 1, wn = w & 1;
  f32x4 acc[4][2];
#pragma unroll
  for (int i = 0; i < 4; ++i)
#pragma unroll
    for (int j = 0; j < 2; ++j) acc[i][j] = (f32x4){0.f, 0.f, 0.f, 0.f};

  const char* aB = (const char*)A + ((size_t)(bm * 128 + (lane >> 3)) << 11) +
                   (((lane & 7) ^ (lane >> 3)) << 4);
  const char* bB = (const char*)Wp + ((size_t)(bn * 64 + (lane >> 3)) << 11) +
                   (((lane & 7) ^ (lane >> 3)) << 4);
  const int ldsBase = w * 1024;
  for (int kt = 0; kt < 16; ++kt) {
    const int ko = kt * 128;
#pragma unroll
    for (int c = 0; c < 4; ++c)
      gload16(aB + ((size_t)(c * 32 + w * 8) << 11) + ko, sA + c * 4096 + ldsBase);
#pragma unroll
    for (int c = 0; c < 2; ++c)
      gload16(bB + ((size_t)(c * 32 + w * 8) << 11) + ko, sB + c * 4096 + ldsBase);
    __syncthreads();
#pragma unroll
    for (int kk = 0; kk < 2; ++kk) {
      const int ch = ((kk * 4 + (lane >> 4)) ^ (lane & 7)) << 4;
      bf16x8 aF[4], bF[2];
#pragma unroll
      for (int mi = 0; mi < 4; ++mi)
        aF[mi] = *(const bf16x8*)(sA + (wm * 64 + mi * 16 + (lane & 15)) * 128 + ch);
#pragma unroll
      for (int ni = 0; ni < 2; ++ni)
        bF[ni] = *(const bf16x8*)(sB + (wn * 32 + ni * 16 + (lane & 15)) * 128 + ch);
#pragma unroll
      for (int mi = 0; mi < 4; ++mi)
#pragma unroll
        for (int ni = 0; ni < 2; ++ni)
          acc[mi][ni] = __builtin_amdgcn_mfma_f32_16x16x32_bf16(bF[ni], aF[mi], acc[mi][ni], 0, 0, 0);
    }
    __syncthreads();
  }
  const int m0 = bm * 128 + wm * 64 + (lane & 15);
  const int nb = bn * 64 + wn * 32 + ((lane >> 4) << 2);
#pragma unroll
  for (int mi = 0; mi < 4; ++mi)
#pragma unroll
    for (int ni = 0; ni < 2; ++ni) {
      const f32x4 v = acc[mi][ni];
      *(float4*)&C[(size_t)(m0 + mi * 16) * 1024 + nb + ni * 16] =
          make_float4(v[0], v[1], v[2], v[3]);
    }
}

// ---------- flash attention: q=32/wave, max folded into acc-init, lacc MFMA, split-KV=2 ----------
// (R13 structure verbatim: best measured at 50.0 us)
__global__ __launch_bounds__(256, 4) void attn_fused(
    const unsigned short* __restrict__ Qp, const unsigned short* __restrict__ Kp,
    const unsigned short* __restrict__ Vp, unsigned short* __restrict__ Opart,
    float2* __restrict__ ML) {
  const int bid = blockIdx.x;
  const int xcd = bid & 7, idx = bid >> 3;  // idx 0..127
  const int bh = ((idx & 3) << 3) | xcd;    // bh % 8 == xcd
  const int rest = idx >> 2;                // 0..31
  const int half = rest & 1;
  const int qt = rest >> 1;                 // 0..15 (128-row Q blocks)
  __shared__ char smem[32768];
  const int tid = threadIdx.x, w = tid >> 6, lane = tid & 63;
  const int q5 = lane & 31, hi = lane >> 5;

  const char* qg = (const char*)Qp + ((size_t)(bh * 32 + qt * 2) << 13);
  const char* kg = (const char*)Kp + ((size_t)(bh * 32 + half * 16) << 13);
  const char* vg = (const char*)Vp + ((size_t)(bh * 32 + half * 16) << 13);

  // stage 2 Q tiles (16 KB), pull frags (lane-linear), then smem becomes KV dbuf
#pragma unroll
  for (int t = 0; t < 4; ++t)
    gload16(qg + (w * 4 + t) * 1024 + lane * 16, smem + (w * 4 + t) * 1024);
  __syncthreads();
  bf16x8 qf[4];
  {
    const int qbase = (w >> 1) * 8192 + ((w & 1) << 10);
#pragma unroll
    for (int dc = 0; dc < 4; ++dc)
      qf[dc] = *(const bf16x8*)(smem + qbase + (dc << 11) + lane * 16);
  }
  __syncthreads();

#pragma unroll
  for (int t = 0; t < 2; ++t) {
    gload16(kg + (w * 2 + t) * 1024 + lane * 16, smem + (w * 2 + t) * 1024);
    gload16(vg + (w * 2 + t) * 1024 + lane * 16, smem + 16384 + (w * 2 + t) * 1024);
  }

  // ones fragment for l-sum MFMA (bf16 1.0 = 0x3F80)
  const u32x4 onesw = {0x3F803F80u, 0x3F803F80u, 0x3F803F80u, 0x3F803F80u};
  const bf16x8 ones = __builtin_bit_cast(bf16x8, onesw);

  f32x16 o0 = {0,0,0,0,0,0,0,0,0,0,0,0,0,0,0,0};
  f32x16 o1 = {0,0,0,0,0,0,0,0,0,0,0,0,0,0,0,0};
  f32x16 lacc = {0,0,0,0,0,0,0,0,0,0,0,0,0,0,0,0};  // row sums of P~; read reg 0 only
  float m = 0.f;        // running max in log2 domain (scores bounded by ~11.6)
  float negm = 0.f;     // -m, the S-accumulator init value

  for (int kt = 0; kt < 16; ++kt) {
    const int cur = kt & 1;
    const int kOff = cur * 8192;
    const int vOff = 16384 + cur * 8192;
    __syncthreads();
    if (kt < 15) {
      const int kN = (cur ^ 1) * 8192, vN = 16384 + (cur ^ 1) * 8192;
#pragma unroll
      for (int t = 0; t < 2; ++t) {
        gload16(kg + (size_t)(kt + 1) * 8192 + (w * 2 + t) * 1024 + lane * 16,
                smem + kN + (w * 2 + t) * 1024);
        gload16(vg + (size_t)(kt + 1) * 8192 + (w * 2 + t) * 1024 + lane * 16,
                smem + vN + (w * 2 + t) * 1024);
      }
    }
    // S^T = K * Q^T + (-m)  (log2 domain, max pre-subtracted via acc init)
    f32x16 s0, s1;
#pragma unroll
    for (int r = 0; r < 16; ++r) { s0[r] = negm; s1[r] = negm; }
    __builtin_amdgcn_s_setprio(1);
#pragma unroll
    for (int dc = 0; dc < 4; ++dc) {
      const bf16x8 kf0 = *(const bf16x8*)(smem + kOff + (dc << 11) + lane * 16);
      const bf16x8 kf1 = *(const bf16x8*)(smem + kOff + (dc << 11) + 1024 + lane * 16);
      s0 = __builtin_amdgcn_mfma_f32_32x32x16_bf16(kf0, qf[dc], s0, 0, 0, 0);
      s1 = __builtin_amdgcn_mfma_f32_32x32x16_bf16(kf1, qf[dc], s1, 0, 0, 0);
    }
    __builtin_amdgcn_s_setprio(0);
    // shifted row max (values are S - m): v_max3 tree + cross-half swap
    float tt[12];
#pragma unroll
    for (int r = 0; r < 10; ++r) {
      const float a = (3 * r) < 16 ? s0[(3 * r) & 15] : s1[(3 * r) & 15];
      const float b = (3 * r + 1) < 16 ? s0[(3 * r + 1) & 15] : s1[(3 * r + 1) & 15];
      const float c = (3 * r + 2) < 16 ? s0[(3 * r + 2) & 15] : s1[(3 * r + 2) & 15];
      tt[r] = max3(a, b, c);
    }
    tt[10] = s1[14]; tt[11] = s1[15];
    tt[0] = max3(tt[0], tt[1], tt[2]);
    tt[1] = max3(tt[3], tt[4], tt[5]);
    tt[2] = max3(tt[6], tt[7], tt[8]);
    tt[3] = max3(tt[9], tt[10], tt[11]);
    const float loc = fmaxf(max3(tt[0], tt[1], tt[2]), tt[3]);
    const float mx = fmaxf(loc, __shfl_xor(loc, 32));  // = rowmax(S) - m
    if (__any(mx > 8.f)) {  // defer-max: rescale only when max grows materially
      const float exc = fmaxf(mx, 0.f);
      const float corr = ex2(-exc);
      lacc[0] *= corr;  // only reg 0 is ever read
#pragma unroll
      for (int r = 0; r < 16; ++r) { o0[r] *= corr; o1[r] *= corr; }
#pragma unroll
      for (int r = 0; r < 16; ++r) { s0[r] -= exc; s1[r] -= exc; }
      m += exc;
      negm = -m;
    }
    unsigned pk[4][4];
#define DO_CHUNK(c, SV, B)                                      \
  {                                                             \
    float p0 = ex2(SV[B + 0]);                                  \
    float p1 = ex2(SV[B + 1]);                                  \
    float p2 = ex2(SV[B + 2]);                                  \
    float p3 = ex2(SV[B + 3]);                                  \
    float p4 = ex2(SV[B + 4]);                                  \
    float p5 = ex2(SV[B + 5]);                                  \
    float p6 = ex2(SV[B + 6]);                                  \
    float p7 = ex2(SV[B + 7]);                                  \
    unsigned a0 = cvtpk2(p0, p1), a1 = cvtpk2(p2, p3);          \
    unsigned b0 = cvtpk2(p4, p5), b1 = cvtpk2(p6, p7);          \
    plswap(a0, b0);                                             \
    plswap(a1, b1);                                             \
    pk[c][0] = a0; pk[c][1] = a1; pk[c][2] = b0; pk[c][3] = b1; \
  }
    DO_CHUNK(0, s0, 0)
    DO_CHUNK(1, s0, 8)
    DO_CHUNK(2, s1, 0)
    DO_CHUNK(3, s1, 8)
#undef DO_CHUNK
    // O^T += V^T * P^T ; l += ones * P^T (row sums in matrix pipe)
    __builtin_amdgcn_s_setprio(1);
#pragma unroll
    for (int kk = 0; kk < 4; ++kk) {
      const bf16x8 vf0 = *(const bf16x8*)(smem + vOff + (kk << 11) + lane * 16);
      const bf16x8 vf1 = *(const bf16x8*)(smem + vOff + (kk << 11) + 1024 + lane * 16);
      const u32x4 pw = {pk[kk][0], pk[kk][1], pk[kk][2], pk[kk][3]};
      const bf16x8 pb = __builtin_bit_cast(bf16x8, pw);
      o0 = __builtin_amdgcn_mfma_f32_32x32x16_bf16(vf0, pb, o0, 0, 0, 0);
      o1 = __builtin_amdgcn_mfma_f32_32x32x16_bf16(vf1, pb, o1, 0, 0, 0);
      lacc = __builtin_amdgcn_mfma_f32_32x32x16_bf16(ones, pb, lacc, 0, 0, 0);
    }
    __builtin_amdgcn_s_setprio(0);
  }

  const float l = lacc[0];
  const float invl = 1.f / l;
  const int q = qt * 128 + w * 32 + q5;
  const size_t prow = (size_t)(half * 32 + bh) * 2048 + q;
  unsigned short* ob = Opart + prow * 64;
#pragma unroll
  for (int g = 0; g < 4; ++g) {
    unsigned d0 = cvtpk2(o0[4 * g + 0] * invl, o0[4 * g + 1] * invl);
    unsigned d1 = cvtpk2(o0[4 * g + 2] * invl, o0[4 * g + 3] * invl);
    *(uint2*)(ob + 8 * g + 4 * hi) = make_uint2(d0, d1);
    unsigned e0 = cvtpk2(o1[4 * g + 0] * invl, o1[4 * g + 1] * invl);
    unsigned e1 = cvtpk2(o1[4 * g + 2] * invl, o1[4 * g + 3] * invl);
    *(uint2*)(ob + 32 + 8 * g + 4 * hi) = make_uint2(e0, e1);
  }
  if (hi == 0) ML[prow] = make_float2(m, l);
}

// ---------- merge the two KV-half partials ----------
__global__ __launch_bounds__(256) void attn_merge(const unsigned short* __restrict__ Op,
                                                  const float2* __restrict__ ML,
                                                  unsigned short* __restrict__ O) {
  const int gid = blockIdx.x * 256 + threadIdx.x;
  const int row = gid >> 3, sub = gid & 7;
  float2 ml[2];
  float mm = -1e30f;
#pragma unroll
  for (int p = 0; p < 2; ++p) {
    ml[p] = ML[p * 65536 + row];
    mm = fmaxf(mm, ml[p].x);
  }
  float wgt[2], wsum = 0.f;
#pragma unroll
  for (int p = 0; p < 2; ++p) {
    wgt[p] = ml[p].y * ex2(ml[p].x - mm);
    wsum += wgt[p];
  }
  const float inv = 1.f / wsum;
  float r[8] = {0.f, 0.f, 0.f, 0.f, 0.f, 0.f, 0.f, 0.f};
#pragma unroll
  for (int p = 0; p < 2; ++p) {
    const uint4 a = *(const uint4*)(Op + ((size_t)(p * 65536) + row) * 64 + sub * 8);
    const unsigned av[4] = {a.x, a.y, a.z, a.w};
#pragma unroll
    for (int j = 0; j < 4; ++j) {
      r[2 * j] += wgt[p] * bf2f((unsigned short)(av[j] & 0xffff));
      r[2 * j + 1] += wgt[p] * bf2f((unsigned short)(av[j] >> 16));
    }
  }
  unsigned ov[4];
#pragma unroll
  for (int j = 0; j < 4; ++j)
    ov[j] = cvtpk2(r[2 * j] * inv, r[2 * j + 1] * inv);
  const int bh = row >> 11, q = row & 2047, bb = bh >> 4, h = bh & 15;
  *(uint4*)(O + ((size_t)(bb * 2048 + q) * 1024 + h * 64 + sub * 8)) =
      make_uint4(ov[0], ov[1], ov[2], ov[3]);
}

// ---------- launch ----------
extern "C" void kernel_launch(void* const* d_in, const int* in_sizes, int n_in,
                              void* d_out, int out_size, void* d_ws, size_t ws_size,
                              hipStream_t stream) {
  const float* xq = (const float*)d_in[0];
  const float* xk = (const float*)d_in[1];
  const float* xv = (const float*)d_in[2];
  const float* wq = (const float*)d_in[3];
  const float* wk = (const float*)d_in[4];
  const float* wv = (const float*)d_in[5];
  const float* wp = (const float*)d_in[6];

  const size_t NX = 4194304;  // B*N*D
  const size_t NW = 1048576;  // D*D
  unsigned short* base = (unsigned short*)d_ws;
  unsigned short* xqb = base;
  unsigned short* xkb = base + NX;
  unsigned short* xvb = base + 2 * NX;
  unsigned short* wqb = base + 3 * NX;
  unsigned short* wkb = wqb + NW;
  unsigned short* wvb = wkb + NW;
  unsigned short* wpb = base + 3 * NX + 4 * NW;  // beyond opart region
  unsigned short* qh = wpb + NW;
  unsigned short* kh = qh + NX;
  unsigned short* vt = kh + NX;
  unsigned short* obf = vt + NX;
  float2* ml = (float2*)(obf + NX);
  unsigned short* opart = base;  // aliases dead x bf16 buffers (2*NX used)

  cvt7<<<dim3(512, 7), 256, 0, stream>>>(xq, xk, xv, wq, wk, wv, wp, (ushort4*)xqb,
                                         (ushort4*)xkb, (ushort4*)xvb, (ushort4*)wqb,
                                         (ushort4*)wkb, (ushort4*)wvb, (ushort4*)wpb,
                                         (int)(NX / 4), (int)(NW / 4));

  gemm_qkv<<<dim3(8, 32, 3), 256, 0, stream>>>(xqb, xkb, xvb, wqb, wkb, wvb, qh, kh, vt);

  attn_fused<<<1024, 256, 0, stream>>>(qh, kh, vt, opart, ml);
  attn_merge<<<2048, 256, 0, stream>>>(opart, ml, obf);

  gemm_out<<<dim3(16, 32), 256, 0, stream>>>(obf, wpb, (float*)d_out);
}